// Round 5
// baseline (7214.304 us; speedup 1.0000x reference)
//
#include <hip/hip_runtime.h>
#include <hip/hip_bf16.h>

#define HH 128
#define WW 128
#define NPIX 16384

using bf16 = __hip_bfloat16;

__device__ __forceinline__ float b2f(bf16 x){ return __bfloat162float(x); }
__device__ __forceinline__ bf16 f2b(float x){ return __float2bfloat16(x); }
__device__ __forceinline__ float hswish(float x){
  float t = fminf(fmaxf(x + 3.0f, 0.0f), 6.0f);
  return x * t * (1.0f/6.0f);
}

// ---- shared 3x3 conv body: one output channel row, weights in LDS ----------
__device__ __forceinline__ float conv3x3_px(
    const float* __restrict__ src, const float* __restrict__ wsh,
    int n, float bias)
{
  const int y = n >> 7, x = n & 127;
  const float* in = src + n;
  const bool yl = y > 0, yh = y < HH-1, xl = x > 0, xh = x < WW-1;
  float acc = bias;
  for (int ci = 0; ci < 128; ++ci) {
    const float* p = in + (size_t)ci*NPIX;
    const float* wr = wsh + ci*9;
    float c00 = (yl&&xl) ? p[-WW-1] : 0.f;
    float c01 = yl       ? p[-WW  ] : 0.f;
    float c02 = (yl&&xh) ? p[-WW+1] : 0.f;
    float c10 = xl       ? p[-1]    : 0.f;
    float c11 =            p[0];
    float c12 = xh       ? p[1]     : 0.f;
    float c20 = (yh&&xl) ? p[WW-1]  : 0.f;
    float c21 = yh       ? p[WW  ]  : 0.f;
    float c22 = (yh&&xh) ? p[WW+1]  : 0.f;
    acc += wr[0]*c00 + wr[1]*c01 + wr[2]*c02
         + wr[3]*c10 + wr[4]*c11 + wr[5]*c12
         + wr[6]*c20 + wr[7]*c21 + wr[8]*c22;
  }
  return acc;
}

// map original qkv channel c (0..383) -> conv source/weights/bias row
__device__ __forceinline__ void qkv_src(
    int c, const float* refB, const float* othB,
    const float* wq, const float* bq, const float* wk, const float* bk,
    const float* wv, const float* bv,
    const float** src, const float** wrow, float* bias)
{
  if (c < 128)      { *src = refB; *wrow = wq + (size_t)c*1152;       *bias = bq[c]; }
  else if (c < 256) { *src = othB; *wrow = wk + (size_t)(c-128)*1152; *bias = bk[c-128]; }
  else              { *src = othB; *wrow = wv + (size_t)(c-256)*1152; *bias = bv[c-256]; }
}

// ---- conv for k/v attention channels (c%24 >= 8): kvbuf[g*16+r], g<16,r<16 -
__global__ __launch_bounds__(256) void k_conv_kv(
    const float* __restrict__ refB, const float* __restrict__ othB,
    const float* __restrict__ wq, const float* __restrict__ bq,
    const float* __restrict__ wk, const float* __restrict__ bk,
    const float* __restrict__ wv, const float* __restrict__ bv,
    bf16* __restrict__ kvbuf)
{
  const int chunk = blockIdx.x & 63;
  const int gr = blockIdx.x >> 6;       // 0..255 = g*16+r
  const int g = gr >> 4, r = gr & 15;
  const int c = g*24 + 8 + r;
  const float* src; const float* wrow; float bias;
  qkv_src(c, refB, othB, wq, bq, wk, bk, wv, bv, &src, &wrow, &bias);
  __shared__ float wsh[1152];
  for (int i = threadIdx.x; i < 1152; i += 256) wsh[i] = wrow[i];
  __syncthreads();
  const int n = chunk*256 + (int)threadIdx.x;
  kvbuf[(size_t)gr*NPIX + n] = f2b(conv3x3_px(src, wsh, n, bias));
}

// ---- conv for q attention channels (c%24 < 8): qbuf[g*8+e] ----------------
__global__ __launch_bounds__(256) void k_conv_q(
    const float* __restrict__ refB, const float* __restrict__ othB,
    const float* __restrict__ wq, const float* __restrict__ bq,
    const float* __restrict__ wk, const float* __restrict__ bk,
    const float* __restrict__ wv, const float* __restrict__ bv,
    bf16* __restrict__ qbuf)
{
  const int chunk = blockIdx.x & 63;
  const int ge = blockIdx.x >> 6;       // 0..127 = g*8+e
  const int g = ge >> 3, e = ge & 7;
  const int c = g*24 + e;
  const float* src; const float* wrow; float bias;
  qkv_src(c, refB, othB, wq, bq, wk, bk, wv, bv, &src, &wrow, &bias);
  __shared__ float wsh[1152];
  for (int i = threadIdx.x; i < 1152; i += 256) wsh[i] = wrow[i];
  __syncthreads();
  const int n = chunk*256 + (int)threadIdx.x;
  qbuf[(size_t)ge*NPIX + n] = f2b(conv3x3_px(src, wsh, n, bias));
}

__device__ __forceinline__ float dw5_px(const bf16* __restrict__ in,
                                        const float* __restrict__ wc, int n)
{
  const int y = n >> 7, x = n & 127;
  float acc = 0.f;
  #pragma unroll
  for (int ky=0; ky<5; ++ky) {
    const int yy = y + ky - 2;
    if (yy < 0 || yy >= HH) continue;
    #pragma unroll
    for (int kx=0; kx<5; ++kx) {
      const int xx = x + kx - 2;
      if (xx < 0 || xx >= WW) continue;
      acc += wc[ky*5+kx] * b2f(in[yy*WW + xx]);
    }
  }
  return acc;
}

// ---- ms k/v channels for 8 attention groups jbase..jbase+7 -----------------
__global__ __launch_bounds__(256) void k_dwpw_kv(
    const bf16* __restrict__ kvbuf, const float* __restrict__ adw,
    const float* __restrict__ apw, bf16* __restrict__ mskv, int jbase)
{
  const int chunk = blockIdx.x & 63;
  const int gl = blockIdx.x >> 6;       // 0..7
  const int jj = jbase + gl;
  __shared__ float dww[16][25];
  __shared__ float pww[16][8];
  for (int i = threadIdx.x; i < 400; i += 256) {
    const int ch = i/25, kk = i%25;
    const int qc = (ch < 8) ? (24*jj + 8 + ch) : (24*jj + 16 + (ch-8));
    dww[ch][kk] = adw[qc*25 + kk];
  }
  for (int i = threadIdx.x; i < 128; i += 256) {
    const int r = i>>3, ii = i&7;
    const int cms = (r < 8) ? (24*jj + 8 + r) : (24*jj + 16 + (r-8));
    pww[r][ii] = apw[cms*8 + ii];
  }
  __syncthreads();
  const int n = chunk*256 + (int)threadIdx.x;
  float dwk[8];
  #pragma unroll
  for (int i=0;i<8;++i)
    dwk[i] = dw5_px(kvbuf + (size_t)(gl*16 + i)*NPIX, dww[i], n);
  #pragma unroll
  for (int e=0;e<8;++e) {
    float s = 0.f;
    #pragma unroll
    for (int i=0;i<8;++i) s += pww[e][i]*dwk[i];
    mskv[(size_t)(gl*16 + e)*NPIX + n] = f2b(s);
  }
  float dwv[8];
  #pragma unroll
  for (int i=0;i<8;++i)
    dwv[i] = dw5_px(kvbuf + (size_t)(gl*16 + 8 + i)*NPIX, dww[8+i], n);
  #pragma unroll
  for (int d=0;d<8;++d) {
    float s = 0.f;
    #pragma unroll
    for (int i=0;i<8;++i) s += pww[8+d][i]*dwv[i];
    mskv[(size_t)(gl*16 + 8 + d)*NPIX + n] = f2b(s);
  }
}

// ---- ms q channels: msq[jj*8+e] = pw grp 3jj over dw of qbuf[jj*8+i] -------
__global__ __launch_bounds__(256) void k_msq(
    const bf16* __restrict__ qbuf, const float* __restrict__ adw,
    const float* __restrict__ apw, bf16* __restrict__ msq)
{
  const int chunk = blockIdx.x & 63;
  const int jj = blockIdx.x >> 6;       // 0..15
  __shared__ float dww[8][25];
  __shared__ float pww[8][8];
  for (int i = threadIdx.x; i < 200; i += 256)
    dww[i/25][i%25] = adw[(24*jj + i/25)*25 + (i%25)];
  if (threadIdx.x < 64)
    pww[threadIdx.x>>3][threadIdx.x&7] = apw[(24*jj + (threadIdx.x>>3))*8 + (threadIdx.x&7)];
  __syncthreads();
  const int n = chunk*256 + (int)threadIdx.x;
  float dwq[8];
  #pragma unroll
  for (int i=0;i<8;++i)
    dwq[i] = dw5_px(qbuf + (size_t)(jj*8 + i)*NPIX, dww[i], n);
  #pragma unroll
  for (int e=0;e<8;++e) {
    float s = 0.f;
    #pragma unroll
    for (int i=0;i<8;++i) s += pww[e][i]*dwq[i];
    msq[(size_t)(jj*8 + e)*NPIX + n] = f2b(s);
  }
}

// ---- kv partial reduction: base has 16-ch groups [k(8) | v(8)] -------------
__global__ __launch_bounds__(256) void k_att_p1(
    const bf16* __restrict__ base, float* __restrict__ part, int g0)
{
  const int s = blockIdx.x & 7;
  const int gl = blockIdx.x >> 3;
  const bf16* bp = base + (size_t)gl*16*NPIX;
  float acc[72];
  #pragma unroll
  for (int i=0;i<72;++i) acc[i]=0.f;
  for (int n = s*2048 + (int)threadIdx.x; n < (s+1)*2048; n += 256) {
    float kk[8], vv[8];
    #pragma unroll
    for (int e=0;e<8;++e) kk[e] = fmaxf(b2f(bp[(size_t)e*NPIX + n]), 0.f);
    #pragma unroll
    for (int d=0;d<8;++d) vv[d] = b2f(bp[(size_t)(8+d)*NPIX + n]);
    #pragma unroll
    for (int d=0;d<8;++d)
      #pragma unroll
      for (int e=0;e<8;++e) acc[d*8+e] += vv[d]*kk[e];
    #pragma unroll
    for (int e=0;e<8;++e) acc[64+e] += kk[e];
  }
  const int lane = threadIdx.x & 63;
  const int wid = threadIdx.x >> 6;
  __shared__ float red[4][72];
  #pragma unroll
  for (int i=0;i<72;++i) {
    float v = acc[i];
    #pragma unroll
    for (int off=32; off>0; off>>=1) v += __shfl_down(v, off, 64);
    if (lane == 0) red[wid][i] = v;
  }
  __syncthreads();
  if (threadIdx.x < 72) {
    part[(size_t)((g0+gl)*8 + s)*72 + threadIdx.x] =
        red[0][threadIdx.x] + red[1][threadIdx.x]
      + red[2][threadIdx.x] + red[3][threadIdx.x];
  }
}

// ---- sum the 8 splits ----
__global__ __launch_bounds__(128) void k_att_p2(
    const float* __restrict__ part, float* __restrict__ kvf)
{
  const int g = blockIdx.x;
  if (threadIdx.x < 72) {
    float sum = 0.f;
    #pragma unroll
    for (int s=0;s<8;++s) sum += part[(size_t)(g*8+s)*72 + threadIdx.x];
    kvf[(size_t)g*72 + threadIdx.x] = sum;
  }
}

// ---- fused att-apply + 1x1 proj 256->128 + BN1 + residual(ref) -------------
// writes fp32 attended into d_out's batch slice
__global__ __launch_bounds__(256) void k_proj(
    const bf16* __restrict__ qbuf, const bf16* __restrict__ msq,
    const float* __restrict__ kvf, const float* __restrict__ w,
    const float* __restrict__ g1, const float* __restrict__ bb1,
    const float* __restrict__ m1, const float* __restrict__ v1,
    const float* __restrict__ refB, float* __restrict__ attd)
{
  const int chunk = blockIdx.x & 63;
  const int cog = blockIdx.x >> 6;             // 0..3
  __shared__ float wsh[32*256];
  __shared__ float kvs[32][72];
  for (int i = threadIdx.x; i < 32*256; i += 256)
    wsh[i] = w[cog*8192 + i];                  // wsh[j*256+ci]
  for (int i = threadIdx.x; i < 32*72; i += 256)
    kvs[i/72][i%72] = kvf[i];
  __syncthreads();
  const int n = chunk*256 + (int)threadIdx.x;
  float acc[32];
  #pragma unroll
  for (int j=0;j<32;++j) acc[j]=0.f;
  for (int g=0; g<32; ++g) {
    const bf16* base = (g < 16) ? qbuf + (size_t)g*8*NPIX
                                : msq + (size_t)(g-16)*8*NPIX;
    float q8[8];
    #pragma unroll
    for (int e=0;e<8;++e) q8[e] = fmaxf(b2f(base[(size_t)e*NPIX + n]), 0.f);
    float den = 0.f;
    #pragma unroll
    for (int e=0;e<8;++e) den += kvs[g][64+e]*q8[e];
    const float inv = 1.0f/(den + 1e-15f);
    float a8[8];
    #pragma unroll
    for (int d=0;d<8;++d) {
      float num = 0.f;
      #pragma unroll
      for (int e=0;e<8;++e) num += kvs[g][d*8+e]*q8[e];
      a8[d] = num*inv;
    }
    #pragma unroll
    for (int j=0;j<32;++j) {
      const float* wr = wsh + j*256 + g*8;
      #pragma unroll
      for (int d=0;d<8;++d) acc[j] += wr[d]*a8[d];
    }
  }
  #pragma unroll
  for (int j=0;j<32;++j) {
    const int co = cog*32 + j;
    const float scale = g1[co] * rsqrtf(v1[co] + 1e-5f);
    const float y = (acc[j] - m1[co])*scale + bb1[co];
    attd[(size_t)co*NPIX + n] = refB[(size_t)co*NPIX + n] + y;
  }
}

// ---- 1x1 mb1 128->768 + hswish (96-channel slab), reads fp32 attended ------
__global__ __launch_bounds__(256) void k_mb1(
    const float* __restrict__ attd, const float* __restrict__ w,
    const float* __restrict__ bias, bf16* __restrict__ h1s, int s)
{
  const int chunk = blockIdx.x & 63;
  const int cog = blockIdx.x >> 6;             // 0..2
  __shared__ float wsh[32*128];
  for (int i = threadIdx.x; i < 32*128; i += 256)
    wsh[i] = w[(s*96 + cog*32)*128 + i];       // wsh[j*128+ci]
  __syncthreads();
  const int n = chunk*256 + (int)threadIdx.x;
  float acc[32];
  #pragma unroll
  for (int j=0;j<32;++j) acc[j]=0.f;
  for (int ci=0; ci<128; ++ci) {
    float x = attd[(size_t)ci*NPIX + n];
    #pragma unroll
    for (int j=0;j<32;++j) acc[j] += wsh[j*128+ci]*x;
  }
  #pragma unroll
  for (int j=0;j<32;++j) {
    const int cg = s*96 + cog*32 + j;
    h1s[(size_t)(cog*32+j)*NPIX + n] = f2b(hswish(acc[j] + bias[cg]));
  }
}

// ---- 3x3 depthwise mb2 + hswish (96-channel slab) --------------------------
__global__ __launch_bounds__(256) void k_mb2(
    const bf16* __restrict__ h1s, const float* __restrict__ w,
    const float* __restrict__ bias, bf16* __restrict__ h2s, int s)
{
  const int idx = blockIdx.x*256 + (int)threadIdx.x;  // cl*NPIX+n, cl<96
  const int n = idx & (NPIX-1);
  const int cl = idx >> 14;
  const int cg = s*96 + cl;
  const int y = n >> 7, x = n & 127;
  const bf16* in = h1s + (size_t)cl*NPIX;
  const float* wc = w + cg*9;
  float acc = bias[cg];
  #pragma unroll
  for (int ky=0; ky<3; ++ky) {
    const int yy = y + ky - 1;
    if (yy < 0 || yy >= HH) continue;
    #pragma unroll
    for (int kx=0; kx<3; ++kx) {
      const int xx = x + kx - 1;
      if (xx < 0 || xx >= WW) continue;
      acc += wc[ky*3+kx] * b2f(in[yy*WW + xx]);
    }
  }
  h2s[idx] = f2b(hswish(acc));
}

// ---- 1x1 mb3 partial: acc (+)= W3[:, slab] . h2s ---------------------------
__global__ __launch_bounds__(256) void k_mb3p(
    const bf16* __restrict__ h2s, const float* __restrict__ w,
    float* __restrict__ accb, int s)
{
  const int chunk = blockIdx.x & 63;
  const int cog = blockIdx.x >> 6;             // 0..3
  __shared__ float wsh[32*96];
  for (int i = threadIdx.x; i < 32*96; i += 256) {
    const int j = i / 96, ci = i % 96;
    wsh[i] = w[(cog*32 + j)*768 + s*96 + ci];
  }
  __syncthreads();
  const int n = chunk*256 + (int)threadIdx.x;
  float sum[32];
  #pragma unroll
  for (int j=0;j<32;++j) sum[j]=0.f;
  for (int ci=0; ci<96; ++ci) {
    float x = b2f(h2s[(size_t)ci*NPIX + n]);
    #pragma unroll
    for (int j=0;j<32;++j) sum[j] += wsh[j*96+ci]*x;
  }
  #pragma unroll
  for (int j=0;j<32;++j) {
    const size_t o = (size_t)(cog*32+j)*NPIX + n;
    if (s == 0) accb[o] = sum[j];
    else        accb[o] += sum[j];
  }
}

// ---- BN2 + residual(attended) -> out (in-place over fp32 attd) -------------
__global__ __launch_bounds__(256) void k_bnres(
    const float* __restrict__ accb, const float* __restrict__ g2,
    const float* __restrict__ bn_b, const float* __restrict__ m2,
    const float* __restrict__ v2, float* __restrict__ attd_out)
{
  const int idx = blockIdx.x*256 + (int)threadIdx.x;  // co*NPIX+n, co<128
  const int co = idx >> 14;
  const float scale = g2[co] * rsqrtf(v2[co] + 1e-5f);
  const float y = (accb[idx] - m2[co])*scale + bn_b[co];
  attd_out[idx] = attd_out[idx] + y;
}

extern "C" void kernel_launch(void* const* d_in, const int* in_sizes, int n_in,
                              void* d_out, int out_size, void* d_ws, size_t ws_size,
                              hipStream_t stream)
{
  const float* ref = (const float*)d_in[0];
  const float* oth = (const float*)d_in[1];
  const float* wq  = (const float*)d_in[2];
  const float* bq  = (const float*)d_in[3];
  const float* wk  = (const float*)d_in[4];
  const float* bk  = (const float*)d_in[5];
  const float* wv  = (const float*)d_in[6];
  const float* bv  = (const float*)d_in[7];
  const float* adw = (const float*)d_in[8];
  const float* apw = (const float*)d_in[9];
  const float* pjw = (const float*)d_in[10];
  const float* g1  = (const float*)d_in[11];
  const float* b1  = (const float*)d_in[12];
  const float* m1  = (const float*)d_in[13];
  const float* v1  = (const float*)d_in[14];
  const float* w1  = (const float*)d_in[15];
  const float* bb1 = (const float*)d_in[16];
  const float* w2  = (const float*)d_in[17];
  const float* bb2 = (const float*)d_in[18];
  const float* w3  = (const float*)d_in[19];
  const float* g2  = (const float*)d_in[20];
  const float* b2p = (const float*)d_in[21];
  const float* m2  = (const float*)d_in[22];
  const float* v2  = (const float*)d_in[23];

  char* ws = (char*)d_ws;
  // Per-batch layout, PEAK 14.68 MiB:
  // attention phase:
  //   kvbuf @ [0,        8388608)  bf16 256ch (16g x 16r: k8|v8)
  //   mskv  @ [8388608, 12582912)  bf16 128ch (8 groups x 16r), two halves
  //   part  @ [12582912,12656640)  fp32 32g x 8s x 72
  //   kvf   @ [12656640,12665856)  fp32 32g x 72
  // proj phase (kvbuf/mskv dead):
  //   qbuf  @ [0,        4194304)  bf16 128ch (16g x 8e)
  //   msq   @ [4194304,  8388608)  bf16 128ch
  // mb phase (attd lives in d_out as fp32):
  //   accb  @ [0,        8388608)  fp32 128ch
  //   h1s   @ [8388608, 11534336)  bf16 96ch
  //   h2s   @ [11534336,14680064)  bf16 96ch
  bf16*  kvbuf = (bf16*)(ws + 0);
  bf16*  mskv  = (bf16*)(ws + 8388608);
  float* part  = (float*)(ws + 12582912);
  float* kvf   = (float*)(ws + 12656640);
  bf16*  qbuf  = (bf16*)(ws + 0);
  bf16*  msq   = (bf16*)(ws + 4194304);
  float* accb  = (float*)(ws + 0);
  bf16*  h1s   = (bf16*)(ws + 8388608);
  bf16*  h2s   = (bf16*)(ws + 11534336);

  for (int b = 0; b < 4; ++b) {
    const float* refB = ref + (size_t)b*128*NPIX;
    const float* othB = oth + (size_t)b*128*NPIX;
    float* attd = (float*)d_out + (size_t)b*128*NPIX;

    k_conv_kv<<<16384, 256, 0, stream>>>(refB, othB, wq, bq, wk, bk, wv, bv, kvbuf);
    k_att_p1 <<<128,   256, 0, stream>>>(kvbuf, part, 0);
    k_dwpw_kv<<<512,   256, 0, stream>>>(kvbuf, adw, apw, mskv, 0);
    k_att_p1 <<<64,    256, 0, stream>>>(mskv, part, 16);
    k_dwpw_kv<<<512,   256, 0, stream>>>(kvbuf, adw, apw, mskv, 8);
    k_att_p1 <<<64,    256, 0, stream>>>(mskv, part, 24);
    k_att_p2 <<<32,    128, 0, stream>>>(part, kvf);
    k_conv_q <<<8192,  256, 0, stream>>>(refB, othB, wq, bq, wk, bk, wv, bv, qbuf);
    k_msq    <<<1024,  256, 0, stream>>>(qbuf, adw, apw, msq);
    k_proj   <<<256,   256, 0, stream>>>(qbuf, msq, kvf, pjw, g1, b1, m1, v1, refB, attd);
    for (int s = 0; s < 8; ++s) {
      k_mb1  <<<192,   256, 0, stream>>>(attd, w1, bb1, h1s, s);
      k_mb2  <<<6144,  256, 0, stream>>>(h1s, w2, bb2, h2s, s);
      k_mb3p <<<256,   256, 0, stream>>>(h2s, w3, accb, s);
    }
    k_bnres  <<<8192,  256, 0, stream>>>(accb, g2, b2p, m2, v2, attd);
  }
}

// Round 6
// 3693.700 us; speedup vs baseline: 1.9531x; 1.9531x over previous
//
#include <hip/hip_runtime.h>
#include <hip/hip_bf16.h>

#define HH 128
#define WW 128
#define NPIX 16384

using bf16 = __hip_bfloat16;
typedef __attribute__((ext_vector_type(8))) short short8;
typedef __attribute__((ext_vector_type(4))) float f32x4;

__device__ __forceinline__ float b2f(bf16 x){ return __bfloat162float(x); }
__device__ __forceinline__ bf16 f2b(float x){ return __float2bfloat16(x); }
__device__ __forceinline__ unsigned short f2bu(float x){
  bf16 h = __float2bfloat16(x);
  return __builtin_bit_cast(unsigned short, h);
}
__device__ __forceinline__ float hswish(float x){
  float t = fminf(fmaxf(x + 3.0f, 0.0f), 6.0f);
  return x * t * (1.0f/6.0f);
}

// ---- weight prep: wbf2[c][tap][ci] (bf16) + biasc[384] (fp32) --------------
__global__ __launch_bounds__(256) void k_wprep(
    const float* __restrict__ wq, const float* __restrict__ wk,
    const float* __restrict__ wv, const float* __restrict__ bq,
    const float* __restrict__ bk, const float* __restrict__ bv,
    bf16* __restrict__ wbf2, float* __restrict__ biasc)
{
  const int idx = blockIdx.x*256 + (int)threadIdx.x;
  if (idx < 384)
    biasc[idx] = (idx < 128) ? bq[idx] : (idx < 256 ? bk[idx-128] : bv[idx-256]);
  if (idx < 384*1152) {
    const int c = idx / 1152, rem = idx % 1152;
    const int tap = rem >> 7, ci = rem & 127;
    const float* wsrc = (c < 128) ? wq : (c < 256 ? wk : wv);
    const int cl = (c < 128) ? c : (c < 256 ? c-128 : c-256);
    wbf2[idx] = f2b(wsrc[(size_t)cl*1152 + ci*9 + tap]);
  }
}

// ---- MFMA implicit-GEMM 3x3 conv: all 384 qkv channels, one batch ----------
// tile<2: src=ref, c0=tile*64 (wq rows); tile>=2: src=oth, c0=128+(tile-2)*64
// stores: channel c -> (c%24<8) ? qbuf[(c/24)*8 + c%24] : kvbuf[(c/24)*16 + c%24-8]
#define CSTR 40
#define RSTR 5200   // 130*40
__global__ __launch_bounds__(256) void k_conv(
    const float* __restrict__ refB, const float* __restrict__ othB,
    const bf16* __restrict__ wbf2, const float* __restrict__ biasc,
    bf16* __restrict__ kvbuf, bf16* __restrict__ qbuf)
{
  const int y = blockIdx.x & 127;
  const int tile = blockIdx.x >> 7;            // 0..5
  const float* src = (tile < 2) ? refB : othB;
  const int c0 = (tile < 2) ? tile*64 : 128 + (tile-2)*64;
  __shared__ unsigned short lds[3*RSTR];
  const int tid = threadIdx.x;
  const int lane = tid & 63;
  const int wv4 = tid >> 6;                    // wave 0..3
  const int cw = c0 + wv4*16;
  const int qd = lane >> 4;                    // quad
  const int l15 = lane & 15;

  f32x4 acc[8];
  #pragma unroll
  for (int g=0; g<8; ++g) acc[g] = (f32x4){0.f,0.f,0.f,0.f};

  // x-halo cols (image x=-1 and x=128) are always zero; write once
  if (tid < 192) {
    const int row = tid / 64;
    const int col = ((tid >> 5) & 1) ? 129 : 0;
    const int ci = tid & 31;
    lds[(row*130 + col)*CSTR + ci] = 0;
  }

  const int sx = tid & 127;
  const int sp = tid >> 7;                     // 0..1
  for (int cb = 0; cb < 4; ++cb) {
    __syncthreads();
    #pragma unroll
    for (int row = 0; row < 3; ++row) {
      const int yy = y + row - 1;
      const bool yok = (yy >= 0) && (yy < HH);
      const float* rp = src + (size_t)(cb*32)*NPIX + (size_t)yy*WW + sx;
      for (int cp = sp; cp < 16; cp += 2) {
        float a0 = 0.f, a1 = 0.f;
        if (yok) {
          a0 = rp[(size_t)(2*cp)*NPIX];
          a1 = rp[(size_t)(2*cp+1)*NPIX];
        }
        const unsigned int pk = ((unsigned int)f2bu(a1) << 16) | f2bu(a0);
        *(unsigned int*)&lds[(row*130 + sx + 1)*CSTR + 2*cp] = pk;
      }
    }
    __syncthreads();
    #pragma unroll
    for (int tap = 0; tap < 9; ++tap) {
      const int trow = tap/3, kx = tap%3;
      const short8 af = *(const short8*)(wbf2
          + (size_t)(cw + l15)*1152 + tap*128 + cb*32 + qd*8);
      const int bbase = trow*RSTR + (l15 + kx)*CSTR + qd*8;
      #pragma unroll
      for (int g = 0; g < 8; ++g) {
        const short8 bfr = *(const short8*)&lds[bbase + g*16*CSTR];
        acc[g] = __builtin_amdgcn_mfma_f32_16x16x32_bf16(af, bfr, acc[g], 0, 0, 0);
      }
    }
  }
  #pragma unroll
  for (int r = 0; r < 4; ++r) {
    const int c = cw + qd*4 + r;
    const int gg = c / 24, rr = c % 24;
    bf16* outp = (rr < 8) ? (qbuf + (size_t)(gg*8 + rr)*NPIX)
                          : (kvbuf + (size_t)(gg*16 + (rr-8))*NPIX);
    const float bias = biasc[c];
    #pragma unroll
    for (int g = 0; g < 8; ++g)
      outp[y*WW + g*16 + l15] = f2b(acc[g][r] + bias);
  }
}

__device__ __forceinline__ float dw5_px(const bf16* __restrict__ in,
                                        const float* __restrict__ wc, int n)
{
  const int y = n >> 7, x = n & 127;
  float acc = 0.f;
  #pragma unroll
  for (int ky=0; ky<5; ++ky) {
    const int yy = y + ky - 2;
    if (yy < 0 || yy >= HH) continue;
    #pragma unroll
    for (int kx=0; kx<5; ++kx) {
      const int xx = x + kx - 2;
      if (xx < 0 || xx >= WW) continue;
      acc += wc[ky*5+kx] * b2f(in[yy*WW + xx]);
    }
  }
  return acc;
}

// ---- ms k/v channels for 8 attention groups jbase..jbase+7 -----------------
__global__ __launch_bounds__(256) void k_dwpw_kv(
    const bf16* __restrict__ kvbuf, const float* __restrict__ adw,
    const float* __restrict__ apw, bf16* __restrict__ mskv, int jbase)
{
  const int chunk = blockIdx.x & 63;
  const int gl = blockIdx.x >> 6;       // 0..7
  const int jj = jbase + gl;
  __shared__ float dww[16][25];
  __shared__ float pww[16][8];
  for (int i = threadIdx.x; i < 400; i += 256) {
    const int ch = i/25, kk = i%25;
    const int qc = (ch < 8) ? (24*jj + 8 + ch) : (24*jj + 16 + (ch-8));
    dww[ch][kk] = adw[qc*25 + kk];
  }
  for (int i = threadIdx.x; i < 128; i += 256) {
    const int r = i>>3, ii = i&7;
    const int cms = (r < 8) ? (24*jj + 8 + r) : (24*jj + 16 + (r-8));
    pww[r][ii] = apw[cms*8 + ii];
  }
  __syncthreads();
  const int n = chunk*256 + (int)threadIdx.x;
  float dwk[8];
  #pragma unroll
  for (int i=0;i<8;++i)
    dwk[i] = dw5_px(kvbuf + (size_t)(jj*16 + i)*NPIX, dww[i], n);
  #pragma unroll
  for (int e=0;e<8;++e) {
    float s = 0.f;
    #pragma unroll
    for (int i=0;i<8;++i) s += pww[e][i]*dwk[i];
    mskv[(size_t)(gl*16 + e)*NPIX + n] = f2b(s);
  }
  float dwv[8];
  #pragma unroll
  for (int i=0;i<8;++i)
    dwv[i] = dw5_px(kvbuf + (size_t)(jj*16 + 8 + i)*NPIX, dww[8+i], n);
  #pragma unroll
  for (int d=0;d<8;++d) {
    float s = 0.f;
    #pragma unroll
    for (int i=0;i<8;++i) s += pww[8+d][i]*dwv[i];
    mskv[(size_t)(gl*16 + 8 + d)*NPIX + n] = f2b(s);
  }
}

// ---- ms q channels: msq[jj*8+e] = pw grp 3jj over dw of qbuf[jj*8+i] -------
__global__ __launch_bounds__(256) void k_msq(
    const bf16* __restrict__ qbuf, const float* __restrict__ adw,
    const float* __restrict__ apw, bf16* __restrict__ msq)
{
  const int chunk = blockIdx.x & 63;
  const int jj = blockIdx.x >> 6;       // 0..15
  __shared__ float dww[8][25];
  __shared__ float pww[8][8];
  for (int i = threadIdx.x; i < 200; i += 256)
    dww[i/25][i%25] = adw[(24*jj + i/25)*25 + (i%25)];
  if (threadIdx.x < 64)
    pww[threadIdx.x>>3][threadIdx.x&7] = apw[(24*jj + (threadIdx.x>>3))*8 + (threadIdx.x&7)];
  __syncthreads();
  const int n = chunk*256 + (int)threadIdx.x;
  float dwq[8];
  #pragma unroll
  for (int i=0;i<8;++i)
    dwq[i] = dw5_px(qbuf + (size_t)(jj*8 + i)*NPIX, dww[i], n);
  #pragma unroll
  for (int e=0;e<8;++e) {
    float s = 0.f;
    #pragma unroll
    for (int i=0;i<8;++i) s += pww[e][i]*dwq[i];
    msq[(size_t)(jj*8 + e)*NPIX + n] = f2b(s);
  }
}

// ---- kv partial reduction: base has 16-ch groups [k(8) | v(8)] -------------
__global__ __launch_bounds__(256) void k_att_p1(
    const bf16* __restrict__ base, float* __restrict__ part, int g0)
{
  const int s = blockIdx.x & 7;
  const int gl = blockIdx.x >> 3;
  const bf16* bp = base + (size_t)gl*16*NPIX;
  float acc[72];
  #pragma unroll
  for (int i=0;i<72;++i) acc[i]=0.f;
  for (int n = s*2048 + (int)threadIdx.x; n < (s+1)*2048; n += 256) {
    float kk[8], vv[8];
    #pragma unroll
    for (int e=0;e<8;++e) kk[e] = fmaxf(b2f(bp[(size_t)e*NPIX + n]), 0.f);
    #pragma unroll
    for (int d=0;d<8;++d) vv[d] = b2f(bp[(size_t)(8+d)*NPIX + n]);
    #pragma unroll
    for (int d=0;d<8;++d)
      #pragma unroll
      for (int e=0;e<8;++e) acc[d*8+e] += vv[d]*kk[e];
    #pragma unroll
    for (int e=0;e<8;++e) acc[64+e] += kk[e];
  }
  const int lane = threadIdx.x & 63;
  const int wid = threadIdx.x >> 6;
  __shared__ float red[4][72];
  #pragma unroll
  for (int i=0;i<72;++i) {
    float v = acc[i];
    #pragma unroll
    for (int off=32; off>0; off>>=1) v += __shfl_down(v, off, 64);
    if (lane == 0) red[wid][i] = v;
  }
  __syncthreads();
  if (threadIdx.x < 72) {
    part[(size_t)((g0+gl)*8 + s)*72 + threadIdx.x] =
        red[0][threadIdx.x] + red[1][threadIdx.x]
      + red[2][threadIdx.x] + red[3][threadIdx.x];
  }
}

// ---- sum the 8 splits ----
__global__ __launch_bounds__(128) void k_att_p2(
    const float* __restrict__ part, float* __restrict__ kvf)
{
  const int g = blockIdx.x;
  if (threadIdx.x < 72) {
    float sum = 0.f;
    #pragma unroll
    for (int s=0;s<8;++s) sum += part[(size_t)(g*8+s)*72 + threadIdx.x];
    kvf[(size_t)g*72 + threadIdx.x] = sum;
  }
}

// ---- fused att-apply + 1x1 proj 256->128 + BN1 + residual(ref) -------------
__global__ __launch_bounds__(256) void k_proj(
    const bf16* __restrict__ qbuf, const bf16* __restrict__ msq,
    const float* __restrict__ kvf, const float* __restrict__ w,
    const float* __restrict__ g1, const float* __restrict__ bb1,
    const float* __restrict__ m1, const float* __restrict__ v1,
    const float* __restrict__ refB, float* __restrict__ attd)
{
  const int chunk = blockIdx.x & 63;
  const int cog = blockIdx.x >> 6;             // 0..3
  __shared__ float wsh[32*256];
  __shared__ float kvs[32][72];
  for (int i = threadIdx.x; i < 32*256; i += 256)
    wsh[i] = w[cog*8192 + i];
  for (int i = threadIdx.x; i < 32*72; i += 256)
    kvs[i/72][i%72] = kvf[i];
  __syncthreads();
  const int n = chunk*256 + (int)threadIdx.x;
  float acc[32];
  #pragma unroll
  for (int j=0;j<32;++j) acc[j]=0.f;
  for (int g=0; g<32; ++g) {
    const bf16* base = (g < 16) ? qbuf + (size_t)g*8*NPIX
                                : msq + (size_t)(g-16)*8*NPIX;
    float q8[8];
    #pragma unroll
    for (int e=0;e<8;++e) q8[e] = fmaxf(b2f(base[(size_t)e*NPIX + n]), 0.f);
    float den = 0.f;
    #pragma unroll
    for (int e=0;e<8;++e) den += kvs[g][64+e]*q8[e];
    const float inv = 1.0f/(den + 1e-15f);
    float a8[8];
    #pragma unroll
    for (int d=0;d<8;++d) {
      float num = 0.f;
      #pragma unroll
      for (int e=0;e<8;++e) num += kvs[g][d*8+e]*q8[e];
      a8[d] = num*inv;
    }
    #pragma unroll
    for (int j=0;j<32;++j) {
      const float* wr = wsh + j*256 + g*8;
      #pragma unroll
      for (int d=0;d<8;++d) acc[j] += wr[d]*a8[d];
    }
  }
  #pragma unroll
  for (int j=0;j<32;++j) {
    const int co = cog*32 + j;
    const float scale = g1[co] * rsqrtf(v1[co] + 1e-5f);
    const float y = (acc[j] - m1[co])*scale + bb1[co];
    attd[(size_t)co*NPIX + n] = refB[(size_t)co*NPIX + n] + y;
  }
}

// ---- 1x1 mb1 128->768 + hswish (192-channel slab), reads fp32 attended -----
__global__ __launch_bounds__(256) void k_mb1(
    const float* __restrict__ attd, const float* __restrict__ w,
    const float* __restrict__ bias, bf16* __restrict__ h1s, int s)
{
  const int chunk = blockIdx.x & 63;
  const int cog = blockIdx.x >> 6;             // 0..5
  __shared__ float wsh[32*128];
  for (int i = threadIdx.x; i < 32*128; i += 256)
    wsh[i] = w[(s*192 + cog*32)*128 + i];
  __syncthreads();
  const int n = chunk*256 + (int)threadIdx.x;
  float acc[32];
  #pragma unroll
  for (int j=0;j<32;++j) acc[j]=0.f;
  for (int ci=0; ci<128; ++ci) {
    float x = attd[(size_t)ci*NPIX + n];
    #pragma unroll
    for (int j=0;j<32;++j) acc[j] += wsh[j*128+ci]*x;
  }
  #pragma unroll
  for (int j=0;j<32;++j) {
    const int cg = s*192 + cog*32 + j;
    h1s[(size_t)(cog*32+j)*NPIX + n] = f2b(hswish(acc[j] + bias[cg]));
  }
}

// ---- 3x3 depthwise mb2 + hswish (192-channel slab) -------------------------
__global__ __launch_bounds__(256) void k_mb2(
    const bf16* __restrict__ h1s, const float* __restrict__ w,
    const float* __restrict__ bias, bf16* __restrict__ h2s, int s)
{
  const int idx = blockIdx.x*256 + (int)threadIdx.x;  // cl*NPIX+n, cl<192
  const int n = idx & (NPIX-1);
  const int cl = idx >> 14;
  const int cg = s*192 + cl;
  const int y = n >> 7, x = n & 127;
  const bf16* in = h1s + (size_t)cl*NPIX;
  const float* wc = w + cg*9;
  float acc = bias[cg];
  #pragma unroll
  for (int ky=0; ky<3; ++ky) {
    const int yy = y + ky - 1;
    if (yy < 0 || yy >= HH) continue;
    #pragma unroll
    for (int kx=0; kx<3; ++kx) {
      const int xx = x + kx - 1;
      if (xx < 0 || xx >= WW) continue;
      acc += wc[ky*3+kx] * b2f(in[yy*WW + xx]);
    }
  }
  h2s[idx] = f2b(hswish(acc));
}

// ---- 1x1 mb3 partial: acc (+)= W3[:, slab] . h2s ---------------------------
__global__ __launch_bounds__(256) void k_mb3p(
    const bf16* __restrict__ h2s, const float* __restrict__ w,
    float* __restrict__ accb, int s)
{
  const int chunk = blockIdx.x & 63;
  const int cog = blockIdx.x >> 6;             // 0..3
  __shared__ float wsh[32*192];
  for (int i = threadIdx.x; i < 32*192; i += 256) {
    const int j = i / 192, ci = i % 192;
    wsh[i] = w[(cog*32 + j)*768 + s*192 + ci];
  }
  __syncthreads();
  const int n = chunk*256 + (int)threadIdx.x;
  float sum[32];
  #pragma unroll
  for (int j=0;j<32;++j) sum[j]=0.f;
  for (int ci=0; ci<192; ++ci) {
    float x = b2f(h2s[(size_t)ci*NPIX + n]);
    #pragma unroll
    for (int j=0;j<32;++j) sum[j] += wsh[j*192+ci]*x;
  }
  #pragma unroll
  for (int j=0;j<32;++j) {
    const size_t o = (size_t)(cog*32+j)*NPIX + n;
    if (s == 0) accb[o] = sum[j];
    else        accb[o] += sum[j];
  }
}

// ---- BN2 + residual(attended) -> out (in-place over fp32 attd) -------------
__global__ __launch_bounds__(256) void k_bnres(
    const float* __restrict__ accb, const float* __restrict__ g2,
    const float* __restrict__ bn_b, const float* __restrict__ m2,
    const float* __restrict__ v2, float* __restrict__ attd_out)
{
  const int idx = blockIdx.x*256 + (int)threadIdx.x;  // co*NPIX+n, co<128
  const int co = idx >> 14;
  const float scale = g2[co] * rsqrtf(v2[co] + 1e-5f);
  const float y = (accb[idx] - m2[co])*scale + bn_b[co];
  attd_out[idx] = attd_out[idx] + y;
}

extern "C" void kernel_launch(void* const* d_in, const int* in_sizes, int n_in,
                              void* d_out, int out_size, void* d_ws, size_t ws_size,
                              hipStream_t stream)
{
  const float* ref = (const float*)d_in[0];
  const float* oth = (const float*)d_in[1];
  const float* wq  = (const float*)d_in[2];
  const float* bq  = (const float*)d_in[3];
  const float* wk  = (const float*)d_in[4];
  const float* bk  = (const float*)d_in[5];
  const float* wv  = (const float*)d_in[6];
  const float* bv  = (const float*)d_in[7];
  const float* adw = (const float*)d_in[8];
  const float* apw = (const float*)d_in[9];
  const float* pjw = (const float*)d_in[10];
  const float* g1  = (const float*)d_in[11];
  const float* b1  = (const float*)d_in[12];
  const float* m1  = (const float*)d_in[13];
  const float* v1  = (const float*)d_in[14];
  const float* w1  = (const float*)d_in[15];
  const float* bb1 = (const float*)d_in[16];
  const float* w2  = (const float*)d_in[17];
  const float* bb2 = (const float*)d_in[18];
  const float* w3  = (const float*)d_in[19];
  const float* g2  = (const float*)d_in[20];
  const float* b2p = (const float*)d_in[21];
  const float* m2  = (const float*)d_in[22];
  const float* v2  = (const float*)d_in[23];

  char* ws = (char*)d_ws;
  // Layout (peak 20.94 MB; ws_size >= 25.2 MB proven by R2/R3 evidence):
  //  wbf2  @ [0,        884736)   bf16 384x1152 (conv weights, MFMA order)
  //  biasc @ [884736,   886272)   fp32 384
  //  kvbuf @ [886784,   9275392)  bf16 256 rows (16g x [k8|v8])
  //  qbuf  @ [9275392,  13469696) bf16 128 rows (16g x 8e)
  //  msq   @ [13469696, 17664000) bf16 128 rows
  //  mskv  @ [17664000, 21858304) bf16 128 rows (8-group halves x2)
  //  part  @ [21858304, 21932032) fp32 32x8x72
  //  kvf   @ [21932032, 21941248) fp32 32x72
  // mb phase (kvbuf..mskv dead):
  //  accb  @ [886784,   9275392)  fp32 128ch
  //  h1s   @ [9275392,  15566848) bf16 192ch
  //  h2s   @ [15566848, 21858304) bf16 192ch
  bf16*  wbf2  = (bf16*)(ws + 0);
  float* biasc = (float*)(ws + 884736);
  bf16*  kvbuf = (bf16*)(ws + 886784);
  bf16*  qbuf  = (bf16*)(ws + 9275392);
  bf16*  msq   = (bf16*)(ws + 13469696);
  bf16*  mskv  = (bf16*)(ws + 17664000);
  float* part  = (float*)(ws + 21858304);
  float* kvf   = (float*)(ws + 21932032);
  float* accb  = (float*)(ws + 886784);
  bf16*  h1s   = (bf16*)(ws + 9275392);
  bf16*  h2s   = (bf16*)(ws + 15566848);

  k_wprep<<<1728, 256, 0, stream>>>(wq, wk, wv, bq, bk, bv, wbf2, biasc);

  for (int b = 0; b < 4; ++b) {
    const float* refB = ref + (size_t)b*128*NPIX;
    const float* othB = oth + (size_t)b*128*NPIX;
    float* attd = (float*)d_out + (size_t)b*128*NPIX;

    k_conv   <<<768,   256, 0, stream>>>(refB, othB, wbf2, biasc, kvbuf, qbuf);
    k_att_p1 <<<128,   256, 0, stream>>>(kvbuf, part, 0);
    k_dwpw_kv<<<512,   256, 0, stream>>>(kvbuf, adw, apw, mskv, 0);
    k_att_p1 <<<64,    256, 0, stream>>>(mskv, part, 16);
    k_dwpw_kv<<<512,   256, 0, stream>>>(kvbuf, adw, apw, mskv, 8);
    k_att_p1 <<<64,    256, 0, stream>>>(mskv, part, 24);
    k_att_p2 <<<32,    128, 0, stream>>>(part, kvf);
    k_msq    <<<1024,  256, 0, stream>>>(qbuf, adw, apw, msq);
    k_proj   <<<256,   256, 0, stream>>>(qbuf, msq, kvf, pjw, g1, b1, m1, v1, refB, attd);
    for (int s = 0; s < 4; ++s) {
      k_mb1  <<<384,   256, 0, stream>>>(attd, w1, bb1, h1s, s);
      k_mb2  <<<12288, 256, 0, stream>>>(h1s, w2, bb2, h2s, s);
      k_mb3p <<<256,   256, 0, stream>>>(h2s, w3, accb, s);
    }
    k_bnres  <<<8192,  256, 0, stream>>>(accb, g2, b2p, m2, v2, attd);
  }
}

// Round 7
// 2233.619 us; speedup vs baseline: 3.2299x; 1.6537x over previous
//
#include <hip/hip_runtime.h>
#include <hip/hip_bf16.h>

#define HH 128
#define WW 128
#define NPIX 16384

using bf16 = __hip_bfloat16;
typedef __attribute__((ext_vector_type(8))) short short8;
typedef __attribute__((ext_vector_type(4))) float f32x4;

__device__ __forceinline__ float b2f(bf16 x){ return __bfloat162float(x); }
__device__ __forceinline__ bf16 f2b(float x){ return __float2bfloat16(x); }
__device__ __forceinline__ unsigned short f2bu(float x){
  bf16 h = __float2bfloat16(x);
  return __builtin_bit_cast(unsigned short, h);
}
__device__ __forceinline__ unsigned short bbits(bf16 x){
  return __builtin_bit_cast(unsigned short, x);
}
__device__ __forceinline__ float hswish(float x){
  float t = fminf(fmaxf(x + 3.0f, 0.0f), 6.0f);
  return x * t * (1.0f/6.0f);
}

// ---- weight prep: conv wbf2[c][tap][ci], mb w1b[768][128], w3b[128][768] ---
__global__ __launch_bounds__(256) void k_wprep(
    const float* __restrict__ wq, const float* __restrict__ wk,
    const float* __restrict__ wv, const float* __restrict__ bq,
    const float* __restrict__ bk, const float* __restrict__ bv,
    const float* __restrict__ w1, const float* __restrict__ w3,
    bf16* __restrict__ wbf2, float* __restrict__ biasc,
    bf16* __restrict__ w1b, bf16* __restrict__ w3b)
{
  const int idx = blockIdx.x*256 + (int)threadIdx.x;
  if (idx < 384)
    biasc[idx] = (idx < 128) ? bq[idx] : (idx < 256 ? bk[idx-128] : bv[idx-256]);
  if (idx < 98304) {
    w1b[idx] = f2b(w1[idx]);   // [768][128] ci-contiguous
    w3b[idx] = f2b(w3[idx]);   // [128][768] ci-contiguous
  }
  if (idx < 384*1152) {
    const int c = idx / 1152, rem = idx % 1152;
    const int tap = rem >> 7, ci = rem & 127;
    const float* wsrc = (c < 128) ? wq : (c < 256 ? wk : wv);
    const int cl = (c < 128) ? c : (c < 256 ? c-128 : c-256);
    wbf2[idx] = f2b(wsrc[(size_t)cl*1152 + ci*9 + tap]);
  }
}

// ---- MFMA implicit-GEMM 3x3 conv: all 384 qkv channels, one batch ----------
#define CSTR 40
#define RSTR 5200   // 130*40
__global__ __launch_bounds__(256) void k_conv(
    const float* __restrict__ refB, const float* __restrict__ othB,
    const bf16* __restrict__ wbf2, const float* __restrict__ biasc,
    bf16* __restrict__ kvbuf, bf16* __restrict__ qbuf)
{
  const int y = blockIdx.x & 127;
  const int tile = blockIdx.x >> 7;            // 0..5
  const float* src = (tile < 2) ? refB : othB;
  const int c0 = (tile < 2) ? tile*64 : 128 + (tile-2)*64;
  __shared__ unsigned short lds[3*RSTR];
  const int tid = threadIdx.x;
  const int lane = tid & 63;
  const int wv4 = tid >> 6;
  const int cw = c0 + wv4*16;
  const int qd = lane >> 4;
  const int l15 = lane & 15;

  f32x4 acc[8];
  #pragma unroll
  for (int g=0; g<8; ++g) acc[g] = (f32x4){0.f,0.f,0.f,0.f};

  if (tid < 192) {
    const int row = tid / 64;
    const int col = ((tid >> 5) & 1) ? 129 : 0;
    const int ci = tid & 31;
    lds[(row*130 + col)*CSTR + ci] = 0;
  }

  const int sx = tid & 127;
  const int sp = tid >> 7;
  for (int cb = 0; cb < 4; ++cb) {
    __syncthreads();
    #pragma unroll
    for (int row = 0; row < 3; ++row) {
      const int yy = y + row - 1;
      const bool yok = (yy >= 0) && (yy < HH);
      const float* rp = src + (size_t)(cb*32)*NPIX + (size_t)yy*WW + sx;
      for (int cp = sp; cp < 16; cp += 2) {
        float a0 = 0.f, a1 = 0.f;
        if (yok) {
          a0 = rp[(size_t)(2*cp)*NPIX];
          a1 = rp[(size_t)(2*cp+1)*NPIX];
        }
        const unsigned int pk = ((unsigned int)f2bu(a1) << 16) | f2bu(a0);
        *(unsigned int*)&lds[(row*130 + sx + 1)*CSTR + 2*cp] = pk;
      }
    }
    __syncthreads();
    #pragma unroll
    for (int tap = 0; tap < 9; ++tap) {
      const int trow = tap/3, kx = tap%3;
      const short8 af = *(const short8*)(wbf2
          + (size_t)(cw + l15)*1152 + tap*128 + cb*32 + qd*8);
      const int bbase = trow*RSTR + (l15 + kx)*CSTR + qd*8;
      #pragma unroll
      for (int g = 0; g < 8; ++g) {
        const short8 bfr = *(const short8*)&lds[bbase + g*16*CSTR];
        acc[g] = __builtin_amdgcn_mfma_f32_16x16x32_bf16(af, bfr, acc[g], 0, 0, 0);
      }
    }
  }
  #pragma unroll
  for (int r = 0; r < 4; ++r) {
    const int c = cw + qd*4 + r;
    const int gg = c / 24, rr = c % 24;
    bf16* outp = (rr < 8) ? (qbuf + (size_t)(gg*8 + rr)*NPIX)
                          : (kvbuf + (size_t)(gg*16 + (rr-8))*NPIX);
    const float bias = biasc[c];
    #pragma unroll
    for (int g = 0; g < 8; ++g)
      outp[y*WW + g*16 + l15] = f2b(acc[g][r] + bias);
  }
}

__device__ __forceinline__ float dw5_px(const bf16* __restrict__ in,
                                        const float* __restrict__ wc, int n)
{
  const int y = n >> 7, x = n & 127;
  float acc = 0.f;
  #pragma unroll
  for (int ky=0; ky<5; ++ky) {
    const int yy = y + ky - 2;
    if (yy < 0 || yy >= HH) continue;
    #pragma unroll
    for (int kx=0; kx<5; ++kx) {
      const int xx = x + kx - 2;
      if (xx < 0 || xx >= WW) continue;
      acc += wc[ky*5+kx] * b2f(in[yy*WW + xx]);
    }
  }
  return acc;
}

// ---- ms k/v channels for 8 attention groups jbase..jbase+7 -----------------
__global__ __launch_bounds__(256) void k_dwpw_kv(
    const bf16* __restrict__ kvbuf, const float* __restrict__ adw,
    const float* __restrict__ apw, bf16* __restrict__ mskv, int jbase)
{
  const int chunk = blockIdx.x & 63;
  const int gl = blockIdx.x >> 6;       // 0..7
  const int jj = jbase + gl;
  __shared__ float dww[16][25];
  __shared__ float pww[16][8];
  for (int i = threadIdx.x; i < 400; i += 256) {
    const int ch = i/25, kk = i%25;
    const int qc = (ch < 8) ? (24*jj + 8 + ch) : (24*jj + 16 + (ch-8));
    dww[ch][kk] = adw[qc*25 + kk];
  }
  for (int i = threadIdx.x; i < 128; i += 256) {
    const int r = i>>3, ii = i&7;
    const int cms = (r < 8) ? (24*jj + 8 + r) : (24*jj + 16 + (r-8));
    pww[r][ii] = apw[cms*8 + ii];
  }
  __syncthreads();
  const int n = chunk*256 + (int)threadIdx.x;
  float dwk[8];
  #pragma unroll
  for (int i=0;i<8;++i)
    dwk[i] = dw5_px(kvbuf + (size_t)(jj*16 + i)*NPIX, dww[i], n);
  #pragma unroll
  for (int e=0;e<8;++e) {
    float s = 0.f;
    #pragma unroll
    for (int i=0;i<8;++i) s += pww[e][i]*dwk[i];
    mskv[(size_t)(gl*16 + e)*NPIX + n] = f2b(s);
  }
  float dwv[8];
  #pragma unroll
  for (int i=0;i<8;++i)
    dwv[i] = dw5_px(kvbuf + (size_t)(jj*16 + 8 + i)*NPIX, dww[8+i], n);
  #pragma unroll
  for (int d=0;d<8;++d) {
    float s = 0.f;
    #pragma unroll
    for (int i=0;i<8;++i) s += pww[8+d][i]*dwv[i];
    mskv[(size_t)(gl*16 + 8 + d)*NPIX + n] = f2b(s);
  }
}

// ---- ms q channels ---------------------------------------------------------
__global__ __launch_bounds__(256) void k_msq(
    const bf16* __restrict__ qbuf, const float* __restrict__ adw,
    const float* __restrict__ apw, bf16* __restrict__ msq)
{
  const int chunk = blockIdx.x & 63;
  const int jj = blockIdx.x >> 6;       // 0..15
  __shared__ float dww[8][25];
  __shared__ float pww[8][8];
  for (int i = threadIdx.x; i < 200; i += 256)
    dww[i/25][i%25] = adw[(24*jj + i/25)*25 + (i%25)];
  if (threadIdx.x < 64)
    pww[threadIdx.x>>3][threadIdx.x&7] = apw[(24*jj + (threadIdx.x>>3))*8 + (threadIdx.x&7)];
  __syncthreads();
  const int n = chunk*256 + (int)threadIdx.x;
  float dwq[8];
  #pragma unroll
  for (int i=0;i<8;++i)
    dwq[i] = dw5_px(qbuf + (size_t)(jj*8 + i)*NPIX, dww[i], n);
  #pragma unroll
  for (int e=0;e<8;++e) {
    float s = 0.f;
    #pragma unroll
    for (int i=0;i<8;++i) s += pww[e][i]*dwq[i];
    msq[(size_t)(jj*8 + e)*NPIX + n] = f2b(s);
  }
}

// ---- kv partial reduction --------------------------------------------------
__global__ __launch_bounds__(256) void k_att_p1(
    const bf16* __restrict__ base, float* __restrict__ part, int g0)
{
  const int s = blockIdx.x & 7;
  const int gl = blockIdx.x >> 3;
  const bf16* bp = base + (size_t)gl*16*NPIX;
  float acc[72];
  #pragma unroll
  for (int i=0;i<72;++i) acc[i]=0.f;
  for (int n = s*2048 + (int)threadIdx.x; n < (s+1)*2048; n += 256) {
    float kk[8], vv[8];
    #pragma unroll
    for (int e=0;e<8;++e) kk[e] = fmaxf(b2f(bp[(size_t)e*NPIX + n]), 0.f);
    #pragma unroll
    for (int d=0;d<8;++d) vv[d] = b2f(bp[(size_t)(8+d)*NPIX + n]);
    #pragma unroll
    for (int d=0;d<8;++d)
      #pragma unroll
      for (int e=0;e<8;++e) acc[d*8+e] += vv[d]*kk[e];
    #pragma unroll
    for (int e=0;e<8;++e) acc[64+e] += kk[e];
  }
  const int lane = threadIdx.x & 63;
  const int wid = threadIdx.x >> 6;
  __shared__ float red[4][72];
  #pragma unroll
  for (int i=0;i<72;++i) {
    float v = acc[i];
    #pragma unroll
    for (int off=32; off>0; off>>=1) v += __shfl_down(v, off, 64);
    if (lane == 0) red[wid][i] = v;
  }
  __syncthreads();
  if (threadIdx.x < 72) {
    part[(size_t)((g0+gl)*8 + s)*72 + threadIdx.x] =
        red[0][threadIdx.x] + red[1][threadIdx.x]
      + red[2][threadIdx.x] + red[3][threadIdx.x];
  }
}

// ---- sum the 8 splits ----
__global__ __launch_bounds__(128) void k_att_p2(
    const float* __restrict__ part, float* __restrict__ kvf)
{
  const int g = blockIdx.x;
  if (threadIdx.x < 72) {
    float sum = 0.f;
    #pragma unroll
    for (int s=0;s<8;++s) sum += part[(size_t)(g*8+s)*72 + threadIdx.x];
    kvf[(size_t)g*72 + threadIdx.x] = sum;
  }
}

// ---- fused att-apply + 1x1 proj 256->128 + BN1 + residual(ref) -------------
__global__ __launch_bounds__(256) void k_proj(
    const bf16* __restrict__ qbuf, const bf16* __restrict__ msq,
    const float* __restrict__ kvf, const float* __restrict__ w,
    const float* __restrict__ g1, const float* __restrict__ bb1,
    const float* __restrict__ m1, const float* __restrict__ v1,
    const float* __restrict__ refB, float* __restrict__ attd)
{
  const int chunk = blockIdx.x & 63;
  const int cog = blockIdx.x >> 6;             // 0..3
  __shared__ float wsh[32*256];
  __shared__ float kvs[32][72];
  for (int i = threadIdx.x; i < 32*256; i += 256)
    wsh[i] = w[cog*8192 + i];
  for (int i = threadIdx.x; i < 32*72; i += 256)
    kvs[i/72][i%72] = kvf[i];
  __syncthreads();
  const int n = chunk*256 + (int)threadIdx.x;
  float acc[32];
  #pragma unroll
  for (int j=0;j<32;++j) acc[j]=0.f;
  for (int g=0; g<32; ++g) {
    const bf16* base = (g < 16) ? qbuf + (size_t)g*8*NPIX
                                : msq + (size_t)(g-16)*8*NPIX;
    float q8[8];
    #pragma unroll
    for (int e=0;e<8;++e) q8[e] = fmaxf(b2f(base[(size_t)e*NPIX + n]), 0.f);
    float den = 0.f;
    #pragma unroll
    for (int e=0;e<8;++e) den += kvs[g][64+e]*q8[e];
    const float inv = 1.0f/(den + 1e-15f);
    float a8[8];
    #pragma unroll
    for (int d=0;d<8;++d) {
      float num = 0.f;
      #pragma unroll
      for (int e=0;e<8;++e) num += kvs[g][d*8+e]*q8[e];
      a8[d] = num*inv;
    }
    #pragma unroll
    for (int j=0;j<32;++j) {
      const float* wr = wsh + j*256 + g*8;
      #pragma unroll
      for (int d=0;d<8;++d) acc[j] += wr[d]*a8[d];
    }
  }
  #pragma unroll
  for (int j=0;j<32;++j) {
    const int co = cog*32 + j;
    const float scale = g1[co] * rsqrtf(v1[co] + 1e-5f);
    const float y = (acc[j] - m1[co])*scale + bb1[co];
    attd[(size_t)co*NPIX + n] = refB[(size_t)co*NPIX + n] + y;
  }
}

// ---- MFMA 1x1 mb1: h1s[192 slab] = hswish(W1[slab,:128].attd + b) ----------
__global__ __launch_bounds__(256) void k_mb1_m(
    const float* __restrict__ attd, const bf16* __restrict__ w1b,
    const float* __restrict__ bias, bf16* __restrict__ h1s, int s)
{
  const int pxt = blockIdx.x & 127;
  const int cot = blockIdx.x >> 7;             // 0..2
  const int n0 = pxt*128;
  __shared__ unsigned short lds[128*CSTR];
  const int tid = threadIdx.x;
  const int lane = tid & 63;
  const int wv4 = tid >> 6;
  const int co16 = s*192 + cot*64 + wv4*16;
  const int qd = lane >> 4, l15 = lane & 15;
  f32x4 acc[8];
  #pragma unroll
  for (int g=0; g<8; ++g) acc[g] = (f32x4){0.f,0.f,0.f,0.f};
  const int sx = tid & 127, sp = tid >> 7;
  for (int cb = 0; cb < 4; ++cb) {
    __syncthreads();
    const float* rp = attd + (size_t)(cb*32)*NPIX + n0 + sx;
    for (int cp = sp; cp < 16; cp += 2) {
      const float a0 = rp[(size_t)(2*cp)*NPIX];
      const float a1 = rp[(size_t)(2*cp+1)*NPIX];
      *(unsigned int*)&lds[sx*CSTR + 2*cp] =
          ((unsigned int)f2bu(a1) << 16) | f2bu(a0);
    }
    __syncthreads();
    const short8 af = *(const short8*)(w1b + (size_t)(co16 + l15)*128 + cb*32 + qd*8);
    #pragma unroll
    for (int g = 0; g < 8; ++g) {
      const short8 bfr = *(const short8*)&lds[(g*16 + l15)*CSTR + qd*8];
      acc[g] = __builtin_amdgcn_mfma_f32_16x16x32_bf16(af, bfr, acc[g], 0, 0, 0);
    }
  }
  #pragma unroll
  for (int r = 0; r < 4; ++r) {
    const int co = co16 + qd*4 + r;
    const float bi = bias[co];
    bf16* op = h1s + (size_t)(co - s*192)*NPIX + n0;
    #pragma unroll
    for (int g = 0; g < 8; ++g)
      op[g*16 + l15] = f2b(hswish(acc[g][r] + bi));
  }
}

// ---- 3x3 depthwise mb2 + hswish (192-channel slab) -------------------------
__global__ __launch_bounds__(256) void k_mb2(
    const bf16* __restrict__ h1s, const float* __restrict__ w,
    const float* __restrict__ bias, bf16* __restrict__ h2s, int s)
{
  const int idx = blockIdx.x*256 + (int)threadIdx.x;
  const int n = idx & (NPIX-1);
  const int cl = idx >> 14;
  const int cg = s*192 + cl;
  const int y = n >> 7, x = n & 127;
  const bf16* in = h1s + (size_t)cl*NPIX;
  const float* wc = w + cg*9;
  float acc = bias[cg];
  #pragma unroll
  for (int ky=0; ky<3; ++ky) {
    const int yy = y + ky - 1;
    if (yy < 0 || yy >= HH) continue;
    #pragma unroll
    for (int kx=0; kx<3; ++kx) {
      const int xx = x + kx - 1;
      if (xx < 0 || xx >= WW) continue;
      acc += wc[ky*3+kx] * b2f(in[yy*WW + xx]);
    }
  }
  h2s[idx] = f2b(hswish(acc));
}

// ---- MFMA 1x1 mb3 partial: accb (+)= W3[:, slab] . h2s ---------------------
__global__ __launch_bounds__(256) void k_mb3_m(
    const bf16* __restrict__ h2s, const bf16* __restrict__ w3b,
    float* __restrict__ accb, int s)
{
  const int pxt = blockIdx.x & 127;
  const int cot = blockIdx.x >> 7;             // 0..1
  const int n0 = pxt*128;
  __shared__ unsigned short lds[128*CSTR];
  const int tid = threadIdx.x;
  const int lane = tid & 63;
  const int wv4 = tid >> 6;
  const int co16 = cot*64 + wv4*16;
  const int qd = lane >> 4, l15 = lane & 15;
  f32x4 acc[8];
  #pragma unroll
  for (int g=0; g<8; ++g) acc[g] = (f32x4){0.f,0.f,0.f,0.f};
  const int sx = tid & 127, sp = tid >> 7;
  for (int cb = 0; cb < 6; ++cb) {
    __syncthreads();
    const bf16* rp = h2s + (size_t)(cb*32)*NPIX + n0 + sx;
    for (int cp = sp; cp < 16; cp += 2) {
      const unsigned short a0 = bbits(rp[(size_t)(2*cp)*NPIX]);
      const unsigned short a1 = bbits(rp[(size_t)(2*cp+1)*NPIX]);
      *(unsigned int*)&lds[sx*CSTR + 2*cp] = ((unsigned int)a1 << 16) | a0;
    }
    __syncthreads();
    const short8 af = *(const short8*)(w3b + (size_t)(co16 + l15)*768 + s*192 + cb*32 + qd*8);
    #pragma unroll
    for (int g = 0; g < 8; ++g) {
      const short8 bfr = *(const short8*)&lds[(g*16 + l15)*CSTR + qd*8];
      acc[g] = __builtin_amdgcn_mfma_f32_16x16x32_bf16(af, bfr, acc[g], 0, 0, 0);
    }
  }
  #pragma unroll
  for (int r = 0; r < 4; ++r) {
    const int co = co16 + qd*4 + r;
    float* op = accb + (size_t)co*NPIX + n0;
    if (s == 0) {
      #pragma unroll
      for (int g = 0; g < 8; ++g) op[g*16 + l15] = acc[g][r];
    } else {
      #pragma unroll
      for (int g = 0; g < 8; ++g) op[g*16 + l15] += acc[g][r];
    }
  }
}

// ---- BN2 + residual(attended) -> out (in-place over fp32 attd) -------------
__global__ __launch_bounds__(256) void k_bnres(
    const float* __restrict__ accb, const float* __restrict__ g2,
    const float* __restrict__ bn_b, const float* __restrict__ m2,
    const float* __restrict__ v2, float* __restrict__ attd_out)
{
  const int idx = blockIdx.x*256 + (int)threadIdx.x;
  const int co = idx >> 14;
  const float scale = g2[co] * rsqrtf(v2[co] + 1e-5f);
  const float y = (accb[idx] - m2[co])*scale + bn_b[co];
  attd_out[idx] = attd_out[idx] + y;
}

extern "C" void kernel_launch(void* const* d_in, const int* in_sizes, int n_in,
                              void* d_out, int out_size, void* d_ws, size_t ws_size,
                              hipStream_t stream)
{
  const float* ref = (const float*)d_in[0];
  const float* oth = (const float*)d_in[1];
  const float* wq  = (const float*)d_in[2];
  const float* bq  = (const float*)d_in[3];
  const float* wk  = (const float*)d_in[4];
  const float* bk  = (const float*)d_in[5];
  const float* wv  = (const float*)d_in[6];
  const float* bv  = (const float*)d_in[7];
  const float* adw = (const float*)d_in[8];
  const float* apw = (const float*)d_in[9];
  const float* pjw = (const float*)d_in[10];
  const float* g1  = (const float*)d_in[11];
  const float* b1  = (const float*)d_in[12];
  const float* m1  = (const float*)d_in[13];
  const float* v1  = (const float*)d_in[14];
  const float* w1  = (const float*)d_in[15];
  const float* bb1 = (const float*)d_in[16];
  const float* w2  = (const float*)d_in[17];
  const float* bb2 = (const float*)d_in[18];
  const float* w3  = (const float*)d_in[19];
  const float* g2  = (const float*)d_in[20];
  const float* b2p = (const float*)d_in[21];
  const float* m2  = (const float*)d_in[22];
  const float* v2  = (const float*)d_in[23];

  char* ws = (char*)d_ws;
  // Layout (peak 22.33 MB; ws_size >= 25.25 MB proven by R2/R3 evidence):
  //  wbf2  @ [0,        884736)   bf16 conv weights
  //  biasc @ [884736,   886272)   fp32 384
  //  w1b   @ [886272,  1082880)   bf16 768x128
  //  w3b   @ [1082880, 1279488)   bf16 128x768
  //  kvbuf @ [1279488, 9668096)   bf16 256 rows
  //  qbuf  @ [9668096, 13862400)  bf16 128 rows
  //  msq   @ [13862400,18056704)  bf16 128 rows
  //  mskv  @ [18056704,22251008)  bf16 128 rows
  //  part  @ [22251008,22324736)  fp32
  //  kvf   @ [22324736,22333952)  fp32
  // mb phase (kvbuf..mskv dead):
  //  accb  @ [1279488, 9668096)   fp32 128ch
  //  h1s   @ [9668096, 15959552)  bf16 192ch
  //  h2s   @ [15959552,22251008)  bf16 192ch
  bf16*  wbf2  = (bf16*)(ws + 0);
  float* biasc = (float*)(ws + 884736);
  bf16*  w1b   = (bf16*)(ws + 886272);
  bf16*  w3b   = (bf16*)(ws + 1082880);
  bf16*  kvbuf = (bf16*)(ws + 1279488);
  bf16*  qbuf  = (bf16*)(ws + 9668096);
  bf16*  msq   = (bf16*)(ws + 13862400);
  bf16*  mskv  = (bf16*)(ws + 18056704);
  float* part  = (float*)(ws + 22251008);
  float* kvf   = (float*)(ws + 22324736);
  float* accb  = (float*)(ws + 1279488);
  bf16*  h1s   = (bf16*)(ws + 9668096);
  bf16*  h2s   = (bf16*)(ws + 15959552);

  k_wprep<<<1728, 256, 0, stream>>>(wq, wk, wv, bq, bk, bv, w1, w3, wbf2, biasc, w1b, w3b);

  for (int b = 0; b < 4; ++b) {
    const float* refB = ref + (size_t)b*128*NPIX;
    const float* othB = oth + (size_t)b*128*NPIX;
    float* attd = (float*)d_out + (size_t)b*128*NPIX;

    k_conv   <<<768,   256, 0, stream>>>(refB, othB, wbf2, biasc, kvbuf, qbuf);
    k_att_p1 <<<128,   256, 0, stream>>>(kvbuf, part, 0);
    k_dwpw_kv<<<512,   256, 0, stream>>>(kvbuf, adw, apw, mskv, 0);
    k_att_p1 <<<64,    256, 0, stream>>>(mskv, part, 16);
    k_dwpw_kv<<<512,   256, 0, stream>>>(kvbuf, adw, apw, mskv, 8);
    k_att_p1 <<<64,    256, 0, stream>>>(mskv, part, 24);
    k_att_p2 <<<32,    128, 0, stream>>>(part, kvf);
    k_msq    <<<1024,  256, 0, stream>>>(qbuf, adw, apw, msq);
    k_proj   <<<256,   256, 0, stream>>>(qbuf, msq, kvf, pjw, g1, b1, m1, v1, refB, attd);
    for (int s = 0; s < 4; ++s) {
      k_mb1_m<<<384,   256, 0, stream>>>(attd, w1b, bb1, h1s, s);
      k_mb2  <<<12288, 256, 0, stream>>>(h1s, w2, bb2, h2s, s);
      k_mb3_m<<<256,   256, 0, stream>>>(h2s, w3b, accb, s);
    }
    k_bnres  <<<8192,  256, 0, stream>>>(accb, g2, b2p, m2, v2, attd);
  }
}